// Round 16
// baseline (508.452 us; speedup 1.0000x reference)
//
#include <hip/hip_runtime.h>

typedef unsigned short u16;
typedef __attribute__((ext_vector_type(4))) float f32x4;
typedef __attribute__((ext_vector_type(8))) short bf16x8;
typedef __attribute__((ext_vector_type(8))) unsigned short u16x8;
typedef __attribute__((ext_vector_type(4))) unsigned short u16x4;

__device__ __forceinline__ u16 f2bf(float f) {
  union { float f; unsigned u; } v; v.f = f;
  unsigned r = v.u + 0x7FFFu + ((v.u >> 16) & 1u);
  return (u16)(r >> 16);
}
__device__ __forceinline__ float bf2f(u16 h) {
  union { unsigned u; float f; } v; v.u = ((unsigned)h) << 16; return v.f;
}

__device__ __forceinline__ void gload_lds16(const void* g, void* l) {
  __builtin_amdgcn_global_load_lds((const __attribute__((address_space(1))) void*)g,
                                   (__attribute__((address_space(3))) void*)l, 16, 0, 0);
}

// ---------------- prep kernels ----------------

__global__ void k_zero(u16x8* __restrict__ p, int n8) {
  int i = blockIdx.x * blockDim.x + threadIdx.x;
  int stride = gridDim.x * blockDim.x;
  u16x8 z = (u16x8)0;
  for (; i < n8; i += stride) p[i] = z;
}

__global__ void k_cvt_x(const float* __restrict__ in, u16* __restrict__ out, int n4) {
  int i = blockIdx.x * blockDim.x + threadIdx.x;
  int stride = gridDim.x * blockDim.x;
  const f32x4* in4 = (const f32x4*)in;
  u16x4* out4 = (u16x4*)out;
  for (; i < n4; i += stride) {
    f32x4 v = in4[i];
    u16x4 o;
    o[0] = f2bf(v[0]); o[1] = f2bf(v[1]); o[2] = f2bf(v[2]); o[3] = f2bf(v[3]);
    out4[i] = o;
  }
}

// LDS-tiled transpose: w [K][1024] f32 -> outT [1024][K] bf16, 64x64 tiles.
__global__ void k_prep_wt(const float* __restrict__ wq, const float* __restrict__ wo,
                          const float* __restrict__ wk, const float* __restrict__ wv,
                          u16* __restrict__ WQ1T, u16* __restrict__ WO1T,
                          u16* __restrict__ WK1T, u16* __restrict__ WV1T) {
  __shared__ u16 tile[64][72];
  int bid = blockIdx.x;
  const float* w; u16* o; int K;
  if (bid < 256)      { w = wq; o = WQ1T; K = 1024; }
  else if (bid < 512) { w = wo; o = WO1T; K = 1024; bid -= 256; }
  else if (bid < 704) { w = wk; o = WK1T; K = 768;  bid -= 512; }
  else                { w = wv; o = WV1T; K = 768;  bid -= 704; }
  const int ti = bid >> 4, tj = bid & 15;
  const int t = threadIdx.x;
  const int r = t >> 2, cq = (t & 3) * 16;

  const float* src = w + (size_t)(ti * 64 + r) * 1024 + tj * 64 + cq;
#pragma unroll
  for (int j4 = 0; j4 < 4; ++j4) {
    f32x4 v = *(const f32x4*)(src + j4 * 4);
#pragma unroll
    for (int e = 0; e < 4; ++e) tile[r][cq + j4 * 4 + e] = f2bf(v[e]);
  }
  __syncthreads();

  u16 vals[16];
#pragma unroll
  for (int j = 0; j < 16; ++j) vals[j] = tile[cq + j][r];
  u16* dst = o + (size_t)(tj * 64 + r) * K + ti * 64 + cq;
  *(u16x8*)dst = *(u16x8*)&vals[0];
  *(u16x8*)(dst + 8) = *(u16x8*)&vals[8];
}

// y [1232][768] f32 -> yb bf16 (straight cvt)
__global__ void k_prep_y(const float* __restrict__ y, u16* __restrict__ yb, int n4) {
  int i = blockIdx.x * blockDim.x + threadIdx.x;
  int stride = gridDim.x * blockDim.x;
  const f32x4* in4 = (const f32x4*)y;
  u16x4* out4 = (u16x4*)yb;
  for (; i < n4; i += stride) {
    f32x4 v = in4[i];
    u16x4 o;
    o[0] = f2bf(v[0]); o[1] = f2bf(v[1]); o[2] = f2bf(v[2]); o[3] = f2bf(v[3]);
    out4[i] = o;
  }
}

// ---------------- K+V projections, merged, m97-style 128^2 ----------------
__global__ __launch_bounds__(256, 2) void k_gemm_kv(
    const u16* __restrict__ A,
    const u16* __restrict__ BK1, const float* __restrict__ bkb, u16* __restrict__ KTo,
    const u16* __restrict__ BV1, const float* __restrict__ bvb, u16* __restrict__ VTo)
{
  const int M = 1232, Kdim = 768;
  __shared__ u16 sA[128 * 32];
  __shared__ u16 sB[128 * 32];
  const int t = threadIdx.x;
  const int half = blockIdx.x >= 80;
  const int bb = blockIdx.x - half * 80;
  const u16* B = half ? BV1 : BK1;
  const float* bias = half ? bvb : bkb;
  u16* outp = half ? VTo : KTo;
  const int bm = bb / 8, bn = bb % 8;
  const int m0 = bm * 128, n0 = bn * 128;
  const int l = t & 63, wv_ = t >> 6;
  const int lr = l & 15, lg = l >> 4;
  const int wm = (wv_ >> 1) * 64, wn = (wv_ & 1) * 64;

  const int srow = t >> 2;
  const int ssw = ((t >> 2) & 3) ^ ((t >> 4) & 3);
  const int scol = ((t & 3) ^ ssw) * 8;
  char* ldsA = (char*)sA;
  char* ldsB = (char*)sB;
  const int ldsoff = wv_ * 1024;

  const int swl = (lr & 3) ^ ((lr >> 2) & 3);
  const int rds = (lg ^ swl) * 8;

  f32x4 acc[4][4] = {};

  for (int kt = 0; kt < Kdim / 32; ++kt) {
    const int k0 = kt * 32;
    __syncthreads();
    {
      int r1 = m0 + srow;       if (r1 > M - 1) r1 = M - 1;
      int r2 = m0 + 64 + srow;  if (r2 > M - 1) r2 = M - 1;
      gload_lds16(A + (size_t)r1 * Kdim + k0 + scol, ldsA + 0    + ldsoff);
      gload_lds16(A + (size_t)r2 * Kdim + k0 + scol, ldsA + 4096 + ldsoff);
      gload_lds16(B + (size_t)(n0 + srow) * Kdim + k0 + scol,      ldsB + 0    + ldsoff);
      gload_lds16(B + (size_t)(n0 + 64 + srow) * Kdim + k0 + scol, ldsB + 4096 + ldsoff);
    }
    __syncthreads();
    bf16x8 af[4], bfr[4];
#pragma unroll
    for (int mt = 0; mt < 4; ++mt)
      af[mt] = *(const bf16x8*)&sA[(wm + mt * 16 + lr) * 32 + rds];
#pragma unroll
    for (int nt = 0; nt < 4; ++nt)
      bfr[nt] = *(const bf16x8*)&sB[(wn + nt * 16 + lr) * 32 + rds];
#pragma unroll
    for (int mt = 0; mt < 4; ++mt)
#pragma unroll
      for (int nt = 0; nt < 4; ++nt)
        acc[mt][nt] = __builtin_amdgcn_mfma_f32_16x16x32_bf16(af[mt], bfr[nt], acc[mt][nt], 0, 0, 0);
  }

#pragma unroll
  for (int mt = 0; mt < 4; ++mt) {
#pragma unroll
    for (int nt = 0; nt < 4; ++nt) {
      const int gc = n0 + wn + nt * 16 + lr;
      const float bb2 = bias[gc];
#pragma unroll
      for (int r = 0; r < 4; ++r) {
        const int gr = m0 + wm + mt * 16 + lg * 4 + r;
        const float v = acc[mt][nt][r] + bb2;
        if (gr < M) {
          int bI = gr / 77, s = gr - bI * 77;
          int hh = gc >> 6, d = gc & 63;
          if (!half)
            outp[(((size_t)bI * 16 + hh) * 96 + s) * 64 + d] = f2bf(v);
          else
            outp[(((size_t)bI * 16 + hh) * 64 + d) * 96 + s] = f2bf(v);
        }
      }
    }
  }
}

// ---------------- k_qattn: r15's 4-phase GEMM + fused attention epilogue (verbatim) ----------------
// Standalone function (NOT a template instantiation) to avoid rule-#19 codegen coupling.
__global__ __launch_bounds__(512, 2) void k_qattn(
    const u16* __restrict__ A, const u16* __restrict__ Bp,
    const float* __restrict__ bias, u16* __restrict__ QBo,
    const u16* __restrict__ KT, const u16* __restrict__ VT)
{
  __shared__ char lds[131072];
  const int t = threadIdx.x;
  const int cpx = (int)gridDim.x >> 3;
  const int swz = ((int)blockIdx.x & 7) * cpx + ((int)blockIdx.x >> 3);
  const int bm = swz >> 2, bn = swz & 3;
  const int m0 = bm * 256, n0 = bn * 256;
  const int w = t >> 6, l = t & 63, lr = l & 15, lg = l >> 4;
  const int wm = w >> 2, wn = w & 3;

  const int srow = t >> 3;
  const int scol = ((t & 7) ^ ((t >> 3) & 7)) << 3;
  const int sw0 = ((lg) ^ (lr & 7)) << 4;
  const int sw1 = ((4 + lg) ^ (lr & 7)) << 4;
  const int abase = wm * 128 + lr;
  const int bbase = wn * 64 + lr;

  f32x4 acc[8][4] = {};

#define RD_A(dst, db, mh, ksw) { _Pragma("unroll") for (int q = 0; q < 4; ++q) \
    dst[q] = *(const bf16x8*)(lds + (db) + ((abase + (mh) * 64 + q * 16) << 7) + (ksw)); }
#define RD_B(dst, db, ksw) { _Pragma("unroll") for (int nt = 0; nt < 4; ++nt) \
    dst[nt] = *(const bf16x8*)(lds + (db) + 32768 + ((bbase + nt * 16) << 7) + (ksw)); }
#define STG_A(kt, dn, j) gload_lds16(A + (size_t)(m0 + (j) * 64 + srow) * 1024 + (kt) * 64 + scol, \
                                     lds + (dn) + (j) * 8192 + t * 16)
#define STG_B(kt, dn, j) gload_lds16(Bp + (size_t)(n0 + (j) * 64 + srow) * 1024 + (kt) * 64 + scol, \
                                     lds + (dn) + 32768 + (j) * 8192 + t * 16)
#define MM16(ab, a_, b_) { __builtin_amdgcn_s_setprio(1); \
  _Pragma("unroll") for (int q = 0; q < 4; ++q) \
    _Pragma("unroll") for (int nt = 0; nt < 4; ++nt) \
      acc[(ab) + q][nt] = __builtin_amdgcn_mfma_f32_16x16x32_bf16(a_[q], b_[nt], acc[(ab) + q][nt], 0, 0, 0); \
  __builtin_amdgcn_s_setprio(0); }
#define BAR __builtin_amdgcn_s_barrier()
#define SB0 __builtin_amdgcn_sched_barrier(0)
#define VM2 asm volatile("s_waitcnt vmcnt(2)" ::: "memory")
#define VM4 asm volatile("s_waitcnt vmcnt(4)" ::: "memory")

  STG_B(0, 0, 0); STG_B(0, 0, 1);
  STG_A(0, 0, 0); STG_A(0, 0, 2);
  STG_B(0, 0, 2); STG_B(0, 0, 3);
  STG_A(0, 0, 1); STG_A(0, 0, 3);
  VM2; SB0; BAR;

#pragma unroll 2
  for (int c = 0; c < 16; ++c) {
    const int db = (c & 1) * 65536, dn = db ^ 65536;
    int cn = c + 1; if (cn > 15) cn = 15;
    bf16x8 a_[4], b0[4], b1[4];
    RD_A(a_, db, 0, sw0); RD_B(b0, db, sw0);
    STG_B(cn, dn, 0); STG_B(cn, dn, 1);
    BAR;
    MM16(0, a_, b0);
    BAR;
    RD_A(a_, db, 0, sw1); RD_B(b1, db, sw1);
    STG_A(cn, dn, 0); STG_A(cn, dn, 2);
    VM4; SB0; BAR;
    MM16(0, a_, b1);
    BAR;
    RD_A(a_, db, 1, sw0);
    STG_B(cn, dn, 2); STG_B(cn, dn, 3);
    BAR;
    MM16(4, a_, b0);
    BAR;
    RD_A(a_, db, 1, sw1);
    STG_A(cn, dn, 1); STG_A(cn, dn, 3);
    VM2; SB0; BAR;
    MM16(4, a_, b1);
    BAR;
  }
  asm volatile("s_waitcnt vmcnt(0)" ::: "memory");
  SB0; BAR;

#undef RD_A
#undef RD_B
#undef STG_A
#undef STG_B
#undef MM16
#undef BAR
#undef SB0
#undef VM2
#undef VM4

  // ---- fused attention epilogue (r14/r15, verbatim) ----
  const int hh = (n0 >> 6) + wn;
  const int b = m0 >> 12;
  const u16* gK = KT + (size_t)(b * 16 + hh) * (96 * 64);
  const u16* gV = VT + (size_t)(b * 16 + hh) * (64 * 96);
  u16* Qs = (u16*)(lds + w * 16384);
  u16* Ps = (u16*)(lds + w * 16384 + 8192);

  bf16x8 fk[5][2], fv[4][3];
#pragma unroll
  for (int nt = 0; nt < 5; ++nt)
#pragma unroll
    for (int ks = 0; ks < 2; ++ks)
      fk[nt][ks] = *(const bf16x8*)&gK[(nt * 16 + lr) * 64 + ks * 32 + lg * 8];
#pragma unroll
  for (int nt = 0; nt < 4; ++nt)
#pragma unroll
    for (int ks = 0; ks < 3; ++ks)
      fv[nt][ks] = *(const bf16x8*)&gV[(nt * 16 + lr) * 96 + ks * 32 + lg * 8];

  float bb[4];
#pragma unroll
  for (int nt = 0; nt < 4; ++nt) bb[nt] = bias[n0 + wn * 64 + nt * 16 + lr];

#pragma unroll
  for (int cc = 0; cc < 4; ++cc) {
#pragma unroll
    for (int qq = 0; qq < 2; ++qq)
#pragma unroll
      for (int nt = 0; nt < 4; ++nt)
#pragma unroll
        for (int r = 0; r < 4; ++r)
          Qs[(qq * 16 + lg * 4 + r) * 72 + nt * 16 + lr] =
              f2bf(acc[cc * 2 + qq][nt][r] + bb[nt]);

    bf16x8 aq[2][2];
#pragma unroll
    for (int qq = 0; qq < 2; ++qq)
#pragma unroll
      for (int ks = 0; ks < 2; ++ks)
        aq[qq][ks] = *(const bf16x8*)&Qs[(qq * 16 + lr) * 72 + ks * 32 + lg * 8];

    f32x4 s_[2][5] = {};
#pragma unroll
    for (int nt = 0; nt < 5; ++nt)
#pragma unroll
      for (int ks = 0; ks < 2; ++ks)
#pragma unroll
        for (int qq = 0; qq < 2; ++qq)
          s_[qq][nt] = __builtin_amdgcn_mfma_f32_16x16x32_bf16(aq[qq][ks], fk[nt][ks], s_[qq][nt], 0, 0, 0);
#pragma unroll
    for (int qq = 0; qq < 2; ++qq)
#pragma unroll
      for (int nt = 0; nt < 5; ++nt)
#pragma unroll
        for (int r = 0; r < 4; ++r)
          s_[qq][nt][r] *= 0.125f;
    if (lr >= 13) {
#pragma unroll
      for (int qq = 0; qq < 2; ++qq)
#pragma unroll
        for (int r = 0; r < 4; ++r)
          s_[qq][4][r] = -1e30f;
    }

    float ri[2][4];
#pragma unroll
    for (int qq = 0; qq < 2; ++qq) {
#pragma unroll
      for (int r = 0; r < 4; ++r) {
        float m1 = s_[qq][0][r];
#pragma unroll
        for (int nt = 1; nt < 5; ++nt) m1 = fmaxf(m1, s_[qq][nt][r]);
        m1 = fmaxf(m1, __shfl_xor(m1, 1, 64));
        m1 = fmaxf(m1, __shfl_xor(m1, 2, 64));
        m1 = fmaxf(m1, __shfl_xor(m1, 4, 64));
        m1 = fmaxf(m1, __shfl_xor(m1, 8, 64));
        float s1 = 0.f;
#pragma unroll
        for (int nt = 0; nt < 5; ++nt) {
          float e = __expf(s_[qq][nt][r] - m1);
          s_[qq][nt][r] = e;
          s1 += e;
        }
        s1 += __shfl_xor(s1, 1, 64);
        s1 += __shfl_xor(s1, 2, 64);
        s1 += __shfl_xor(s1, 4, 64);
        s1 += __shfl_xor(s1, 8, 64);
        ri[qq][r] = 1.0f / s1;
      }
    }

#pragma unroll
    for (int qq = 0; qq < 2; ++qq)
#pragma unroll
      for (int nt = 0; nt < 5; ++nt)
#pragma unroll
        for (int r = 0; r < 4; ++r)
          Ps[(qq * 16 + lg * 4 + r) * 104 + nt * 16 + lr] = f2bf(s_[qq][nt][r] * ri[qq][r]);
#pragma unroll
    for (int qq = 0; qq < 2; ++qq)
#pragma unroll
      for (int r = 0; r < 4; ++r)
        Ps[(qq * 16 + lg * 4 + r) * 104 + 80 + lr] = 0;

    f32x4 o_[2][4] = {};
#pragma unroll
    for (int ks = 0; ks < 3; ++ks) {
      bf16x8 ap[2];
#pragma unroll
      for (int qq = 0; qq < 2; ++qq)
        ap[qq] = *(const bf16x8*)&Ps[(qq * 16 + lr) * 104 + ks * 32 + lg * 8];
#pragma unroll
      for (int nt = 0; nt < 4; ++nt)
#pragma unroll
        for (int qq = 0; qq < 2; ++qq)
          o_[qq][nt] = __builtin_amdgcn_mfma_f32_16x16x32_bf16(ap[qq], fv[nt][ks], o_[qq][nt], 0, 0, 0);
    }

#pragma unroll
    for (int qq = 0; qq < 2; ++qq)
#pragma unroll
      for (int nt = 0; nt < 4; ++nt)
#pragma unroll
        for (int r = 0; r < 4; ++r)
          QBo[(size_t)(m0 + wm * 128 + cc * 32 + qq * 16 + lg * 4 + r) * 1024
              + hh * 64 + nt * 16 + lr] = f2bf(o_[qq][nt][r]);
  }
}

// ---------------- k_oproj: r11's 4-slot-ring reg-prefetch GEMM + f32 epilogue (verbatim) ----------------
// Standalone function; in r11's compile unit this exact loop measured 183 us.
__global__ __launch_bounds__(512, 2) void k_oproj(
    const u16* __restrict__ A, const u16* __restrict__ Bp,
    const float* __restrict__ bias, float* __restrict__ outp)
{
  __shared__ char lds[131072];
  const int t = threadIdx.x;
  const int cpx = (int)gridDim.x >> 3;
  const int swz = ((int)blockIdx.x & 7) * cpx + ((int)blockIdx.x >> 3);
  const int bm = swz >> 2, bn = swz & 3;
  const int m0 = bm * 256, n0 = bn * 256;
  const int w = t >> 6, l = t & 63, lr = l & 15, lg = l >> 4;
  const int wm = w >> 2, wn = w & 3;

  const int srow = t >> 2;
  const int scol = ((t & 3) ^ ((t >> 2) & 3) ^ ((t >> 4) & 3)) * 8;
  const int rsw = (lg ^ (lr & 3) ^ ((lr >> 2) & 3)) << 4;
  const int arow = wm * 128 + lr;
  const int brow = wn * 64 + lr;

  f32x4 acc[8][4] = {};

#define RD(dstA, dstB, sbb) { \
  _Pragma("unroll") for (int q = 0; q < 8; ++q) \
    dstA[q] = *(const bf16x8*)(lds + (sbb) + ((arow + q * 16) << 6) + rsw); \
  _Pragma("unroll") for (int nt = 0; nt < 4; ++nt) \
    dstB[nt] = *(const bf16x8*)(lds + (sbb) + 16384 + ((brow + nt * 16) << 6) + rsw); }
#define STAGE(kt, sbb) { \
    gload_lds16(A  + (size_t)(m0 + srow) * 1024 + (kt) * 32 + scol,       lds + (sbb) + t * 16); \
    gload_lds16(A  + (size_t)(m0 + 128 + srow) * 1024 + (kt) * 32 + scol, lds + (sbb) + 8192 + t * 16); \
    gload_lds16(Bp + (size_t)(n0 + srow) * 1024 + (kt) * 32 + scol,       lds + (sbb) + 16384 + t * 16); \
    gload_lds16(Bp + (size_t)(n0 + 128 + srow) * 1024 + (kt) * 32 + scol, lds + (sbb) + 24576 + t * 16); }
#define MM(a_, b_) { __builtin_amdgcn_s_setprio(1); \
  _Pragma("unroll") for (int q = 0; q < 8; ++q) \
    _Pragma("unroll") for (int nt = 0; nt < 4; ++nt) \
      acc[q][nt] = __builtin_amdgcn_mfma_f32_16x16x32_bf16(a_[q], b_[nt], acc[q][nt], 0, 0, 0); \
  __builtin_amdgcn_s_setprio(0); }
#define BAR __builtin_amdgcn_s_barrier()
#define SB0 __builtin_amdgcn_sched_barrier(0)
#define VM8 asm volatile("s_waitcnt vmcnt(8)" ::: "memory")

  bf16x8 aA[8], bA[4], aB[8], bB[4];

  STAGE(0, 0); STAGE(1, 32768); STAGE(2, 65536);
  VM8; SB0; BAR;
  RD(aA, bA, 0);

  int rdo = 32768, sto = 98304;
#pragma unroll 1
  for (int tt = 0; tt < 32; tt += 2) {
    {
      int ks = tt + 3; if (ks > 31) ks = 31;
      STAGE(ks, sto); sto = (sto + 32768) & 131071;
      VM8; SB0; BAR;
      RD(aB, bB, rdo); rdo = (rdo + 32768) & 131071;
      MM(aA, bA);
      BAR;
    }
    {
      int ks = tt + 4; if (ks > 31) ks = 31;
      STAGE(ks, sto); sto = (sto + 32768) & 131071;
      VM8; SB0; BAR;
      RD(aA, bA, rdo); rdo = (rdo + 32768) & 131071;
      MM(aB, bB);
      BAR;
    }
  }
  asm volatile("s_waitcnt vmcnt(0)" ::: "memory");
  SB0;

#undef RD
#undef STAGE
#undef MM
#undef BAR
#undef SB0
#undef VM8

#pragma unroll
  for (int q = 0; q < 8; ++q) {
#pragma unroll
    for (int nt = 0; nt < 4; ++nt) {
      const int gc = n0 + wn * 64 + nt * 16 + lr;
      const float bb = bias[gc];
#pragma unroll
      for (int r = 0; r < 4; ++r) {
        const int gr = m0 + wm * 128 + q * 16 + lg * 4 + r;
        outp[(size_t)gr * 1024 + gc] = acc[q][nt][r] + bb;
      }
    }
  }
}

// ---------------- launch ----------------

extern "C" void kernel_launch(void* const* d_in, const int* in_sizes, int n_in,
                              void* d_out, int out_size, void* d_ws, size_t ws_size,
                              hipStream_t stream) {
  const float* x  = (const float*)d_in[0];
  const float* y  = (const float*)d_in[1];
  const float* wq = (const float*)d_in[2];
  const float* bq = (const float*)d_in[3];
  const float* wk = (const float*)d_in[4];
  const float* bk = (const float*)d_in[5];
  const float* wv = (const float*)d_in[6];
  const float* bv = (const float*)d_in[7];
  const float* wo = (const float*)d_in[8];
  const float* bo = (const float*)d_in[9];

  char* ws = (char*)d_ws;
  u16* QB   = (u16*)(ws + 0);            // 65536x1024 bf16 = 128 MB (attn-out)
  u16* WQ1T = (u16*)(ws + 134217728);    // [1024][1024] bf16, 2 MB
  u16* WO1T = (u16*)(ws + 136314880);    // 2 MB
  u16* WK1T = (u16*)(ws + 138412032);    // [1024][768] bf16, 1.5 MB
  u16* WV1T = (u16*)(ws + 139984896);    // 1.5 MB
  u16* YB   = (u16*)(ws + 141557760);    // [1232][768] bf16, 1.85 MB
  u16* KT   = (u16*)(ws + 143654912);    // [16][16][96][64] bf16, 3 MB
  u16* VT   = (u16*)(ws + 146800640);    // [16][16][64][96] bf16, 3 MB

  u16*   XB  = (u16*)d_out;   // x as bf16, first 128 MB of d_out (consumed before final write)
  float* OUT = (float*)d_out;

  // prep
  k_zero<<<768, 256, 0, stream>>>((u16x8*)KT, 393216);          // zero KT+VT (adjacent, 6 MB)
  k_cvt_x<<<4096, 256, 0, stream>>>(x, XB, 16777216);
  k_prep_wt<<<896, 256, 0, stream>>>(wq, wo, wk, wv, WQ1T, WO1T, WK1T, WV1T);
  k_prep_y<<<924, 256, 0, stream>>>(y, YB, 236544);

  // K+V projections (one launch): M=1232, K=768
  k_gemm_kv<<<160, 256, 0, stream>>>(YB, WK1T, bk, KT, WV1T, bv, VT);

  // Q projection + FUSED ATTENTION -> QB (r15 4-phase core)
  k_qattn<<<1024, 512, 0, stream>>>(XB, WQ1T, bq, QB, KT, VT);

  // output projection -> f32 d_out (r11 ring core)
  k_oproj<<<1024, 512, 0, stream>>>(QB, WO1T, bo, OUT);
}

// Round 17
// 489.549 us; speedup vs baseline: 1.0386x; 1.0386x over previous
//
#include <hip/hip_runtime.h>

typedef unsigned short u16;
typedef __attribute__((ext_vector_type(4))) float f32x4;
typedef __attribute__((ext_vector_type(8))) short bf16x8;
typedef __attribute__((ext_vector_type(8))) unsigned short u16x8;
typedef __attribute__((ext_vector_type(4))) unsigned short u16x4;

__device__ __forceinline__ u16 f2bf(float f) {
  union { float f; unsigned u; } v; v.f = f;
  unsigned r = v.u + 0x7FFFu + ((v.u >> 16) & 1u);
  return (u16)(r >> 16);
}
__device__ __forceinline__ float bf2f(u16 h) {
  union { unsigned u; float f; } v; v.u = ((unsigned)h) << 16; return v.f;
}

__device__ __forceinline__ void gload_lds16(const void* g, void* l) {
  __builtin_amdgcn_global_load_lds((const __attribute__((address_space(1))) void*)g,
                                   (__attribute__((address_space(3))) void*)l, 16, 0, 0);
}

// ---------------- prep kernels ----------------

__global__ void k_zero(u16x8* __restrict__ p, int n8) {
  int i = blockIdx.x * blockDim.x + threadIdx.x;
  int stride = gridDim.x * blockDim.x;
  u16x8 z = (u16x8)0;
  for (; i < n8; i += stride) p[i] = z;
}

__global__ void k_cvt_x(const float* __restrict__ in, u16* __restrict__ out, int n4) {
  int i = blockIdx.x * blockDim.x + threadIdx.x;
  int stride = gridDim.x * blockDim.x;
  const f32x4* in4 = (const f32x4*)in;
  u16x4* out4 = (u16x4*)out;
  for (; i < n4; i += stride) {
    f32x4 v = in4[i];
    u16x4 o;
    o[0] = f2bf(v[0]); o[1] = f2bf(v[1]); o[2] = f2bf(v[2]); o[3] = f2bf(v[3]);
    out4[i] = o;
  }
}

// LDS-tiled transpose: w [K][1024] f32 -> outT [1024][K] bf16, 64x64 tiles.
__global__ void k_prep_wt(const float* __restrict__ wq, const float* __restrict__ wo,
                          const float* __restrict__ wk, const float* __restrict__ wv,
                          u16* __restrict__ WQ1T, u16* __restrict__ WO1T,
                          u16* __restrict__ WK1T, u16* __restrict__ WV1T) {
  __shared__ u16 tile[64][72];
  int bid = blockIdx.x;
  const float* w; u16* o; int K;
  if (bid < 256)      { w = wq; o = WQ1T; K = 1024; }
  else if (bid < 512) { w = wo; o = WO1T; K = 1024; bid -= 256; }
  else if (bid < 704) { w = wk; o = WK1T; K = 768;  bid -= 512; }
  else                { w = wv; o = WV1T; K = 768;  bid -= 704; }
  const int ti = bid >> 4, tj = bid & 15;
  const int t = threadIdx.x;
  const int r = t >> 2, cq = (t & 3) * 16;

  const float* src = w + (size_t)(ti * 64 + r) * 1024 + tj * 64 + cq;
#pragma unroll
  for (int j4 = 0; j4 < 4; ++j4) {
    f32x4 v = *(const f32x4*)(src + j4 * 4);
#pragma unroll
    for (int e = 0; e < 4; ++e) tile[r][cq + j4 * 4 + e] = f2bf(v[e]);
  }
  __syncthreads();

  u16 vals[16];
#pragma unroll
  for (int j = 0; j < 16; ++j) vals[j] = tile[cq + j][r];
  u16* dst = o + (size_t)(tj * 64 + r) * K + ti * 64 + cq;
  *(u16x8*)dst = *(u16x8*)&vals[0];
  *(u16x8*)(dst + 8) = *(u16x8*)&vals[8];
}

// y [1232][768] f32 -> yb bf16 (straight cvt)
__global__ void k_prep_y(const float* __restrict__ y, u16* __restrict__ yb, int n4) {
  int i = blockIdx.x * blockDim.x + threadIdx.x;
  int stride = gridDim.x * blockDim.x;
  const f32x4* in4 = (const f32x4*)y;
  u16x4* out4 = (u16x4*)yb;
  for (; i < n4; i += stride) {
    f32x4 v = in4[i];
    u16x4 o;
    o[0] = f2bf(v[0]); o[1] = f2bf(v[1]); o[2] = f2bf(v[2]); o[3] = f2bf(v[3]);
    out4[i] = o;
  }
}

// ---------------- K+V projections, merged, m97-style 128^2 ----------------
__global__ __launch_bounds__(256, 2) void k_gemm_kv(
    const u16* __restrict__ A,
    const u16* __restrict__ BK1, const float* __restrict__ bkb, u16* __restrict__ KTo,
    const u16* __restrict__ BV1, const float* __restrict__ bvb, u16* __restrict__ VTo)
{
  const int M = 1232, Kdim = 768;
  __shared__ u16 sA[128 * 32];
  __shared__ u16 sB[128 * 32];
  const int t = threadIdx.x;
  const int half = blockIdx.x >= 80;
  const int bb = blockIdx.x - half * 80;
  const u16* B = half ? BV1 : BK1;
  const float* bias = half ? bvb : bkb;
  u16* outp = half ? VTo : KTo;
  const int bm = bb / 8, bn = bb % 8;
  const int m0 = bm * 128, n0 = bn * 128;
  const int l = t & 63, wv_ = t >> 6;
  const int lr = l & 15, lg = l >> 4;
  const int wm = (wv_ >> 1) * 64, wn = (wv_ & 1) * 64;

  const int srow = t >> 2;
  const int ssw = ((t >> 2) & 3) ^ ((t >> 4) & 3);
  const int scol = ((t & 3) ^ ssw) * 8;
  char* ldsA = (char*)sA;
  char* ldsB = (char*)sB;
  const int ldsoff = wv_ * 1024;

  const int swl = (lr & 3) ^ ((lr >> 2) & 3);
  const int rds = (lg ^ swl) * 8;

  f32x4 acc[4][4] = {};

  for (int kt = 0; kt < Kdim / 32; ++kt) {
    const int k0 = kt * 32;
    __syncthreads();
    {
      int r1 = m0 + srow;       if (r1 > M - 1) r1 = M - 1;
      int r2 = m0 + 64 + srow;  if (r2 > M - 1) r2 = M - 1;
      gload_lds16(A + (size_t)r1 * Kdim + k0 + scol, ldsA + 0    + ldsoff);
      gload_lds16(A + (size_t)r2 * Kdim + k0 + scol, ldsA + 4096 + ldsoff);
      gload_lds16(B + (size_t)(n0 + srow) * Kdim + k0 + scol,      ldsB + 0    + ldsoff);
      gload_lds16(B + (size_t)(n0 + 64 + srow) * Kdim + k0 + scol, ldsB + 4096 + ldsoff);
    }
    __syncthreads();
    bf16x8 af[4], bfr[4];
#pragma unroll
    for (int mt = 0; mt < 4; ++mt)
      af[mt] = *(const bf16x8*)&sA[(wm + mt * 16 + lr) * 32 + rds];
#pragma unroll
    for (int nt = 0; nt < 4; ++nt)
      bfr[nt] = *(const bf16x8*)&sB[(wn + nt * 16 + lr) * 32 + rds];
#pragma unroll
    for (int mt = 0; mt < 4; ++mt)
#pragma unroll
      for (int nt = 0; nt < 4; ++nt)
        acc[mt][nt] = __builtin_amdgcn_mfma_f32_16x16x32_bf16(af[mt], bfr[nt], acc[mt][nt], 0, 0, 0);
  }

#pragma unroll
  for (int mt = 0; mt < 4; ++mt) {
#pragma unroll
    for (int nt = 0; nt < 4; ++nt) {
      const int gc = n0 + wn + nt * 16 + lr;
      const float bb2 = bias[gc];
#pragma unroll
      for (int r = 0; r < 4; ++r) {
        const int gr = m0 + wm + mt * 16 + lg * 4 + r;
        const float v = acc[mt][nt][r] + bb2;
        if (gr < M) {
          int bI = gr / 77, s = gr - bI * 77;
          int hh = gc >> 6, d = gc & 63;
          if (!half)
            outp[(((size_t)bI * 16 + hh) * 96 + s) * 64 + d] = f2bf(v);
          else
            outp[(((size_t)bI * 16 + hh) * 64 + d) * 96 + s] = f2bf(v);
        }
      }
    }
  }
}

// ---------------- big GEMM: 256x256, BK=64, 4-phase/tile counted-vmcnt pipeline (r15) ----------------
// Best verified core (r15: 215us fused / ~215us plain, absmax 9.77e-4).
// Ledger: stage during tile c for c+1: ph0:(B0,B1) ph1:(A0,A2) ph2:(B2,B3) ph3:(A1,A3);
// waits before barriers: end-ph1 vmcnt(4), end-ph3 vmcnt(2). sw16 swizzle (0-conflict 128B rows).
// EPI 0: fused attention epilogue. EPI 1: +bias -> f32.
template <int EPI>
__global__ __launch_bounds__(512, 2) void gemm8p(
    const u16* __restrict__ A, const u16* __restrict__ Bp,
    const float* __restrict__ bias, void* __restrict__ outp,
    const u16* __restrict__ KT, const u16* __restrict__ VT)
{
  __shared__ char lds[131072];
  const int t = threadIdx.x;
  const int cpx = (int)gridDim.x >> 3;
  const int swz = ((int)blockIdx.x & 7) * cpx + ((int)blockIdx.x >> 3);
  const int bm = swz >> 2, bn = swz & 3;
  const int m0 = bm * 256, n0 = bn * 256;
  const int w = t >> 6, l = t & 63, lr = l & 15, lg = l >> 4;
  const int wm = w >> 2, wn = w & 3;   // 2 M-waves x 4 N-waves, wave tile 128x64

  const int srow = t >> 3;
  const int scol = ((t & 7) ^ ((t >> 3) & 7)) << 3;   // elems
  const int sw0 = ((lg) ^ (lr & 7)) << 4;
  const int sw1 = ((4 + lg) ^ (lr & 7)) << 4;
  const int abase = wm * 128 + lr;
  const int bbase = wn * 64 + lr;

  f32x4 acc[8][4] = {};

#define RD_A(dst, db, mh, ksw) { _Pragma("unroll") for (int q = 0; q < 4; ++q) \
    dst[q] = *(const bf16x8*)(lds + (db) + ((abase + (mh) * 64 + q * 16) << 7) + (ksw)); }
#define RD_B(dst, db, ksw) { _Pragma("unroll") for (int nt = 0; nt < 4; ++nt) \
    dst[nt] = *(const bf16x8*)(lds + (db) + 32768 + ((bbase + nt * 16) << 7) + (ksw)); }
#define STG_A(kt, dn, j) gload_lds16(A + (size_t)(m0 + (j) * 64 + srow) * 1024 + (kt) * 64 + scol, \
                                     lds + (dn) + (j) * 8192 + t * 16)
#define STG_B(kt, dn, j) gload_lds16(Bp + (size_t)(n0 + (j) * 64 + srow) * 1024 + (kt) * 64 + scol, \
                                     lds + (dn) + 32768 + (j) * 8192 + t * 16)
#define MM16(ab, a_, b_) { __builtin_amdgcn_s_setprio(1); \
  _Pragma("unroll") for (int q = 0; q < 4; ++q) \
    _Pragma("unroll") for (int nt = 0; nt < 4; ++nt) \
      acc[(ab) + q][nt] = __builtin_amdgcn_mfma_f32_16x16x32_bf16(a_[q], b_[nt], acc[(ab) + q][nt], 0, 0, 0); \
  __builtin_amdgcn_s_setprio(0); }
#define BAR __builtin_amdgcn_s_barrier()
#define SB0 __builtin_amdgcn_sched_barrier(0)
#define VM2 asm volatile("s_waitcnt vmcnt(2)" ::: "memory")
#define VM4 asm volatile("s_waitcnt vmcnt(4)" ::: "memory")

  // prologue: stage tile 0 in ledger order; vmcnt(2) leaves (A1,A3)(t0) flying.
  STG_B(0, 0, 0); STG_B(0, 0, 1);
  STG_A(0, 0, 0); STG_A(0, 0, 2);
  STG_B(0, 0, 2); STG_B(0, 0, 3);
  STG_A(0, 0, 1); STG_A(0, 0, 3);
  VM2; SB0; BAR;

#pragma unroll 2
  for (int c = 0; c < 16; ++c) {
    const int db = (c & 1) * 65536, dn = db ^ 65536;
    int cn = c + 1; if (cn > 15) cn = 15;   // tail: dummy re-stage of t15 into dead buf
    bf16x8 a_[4], b0[4], b1[4];
    // ph0: (mh0, kk0); stage B0,B1(c+1)
    RD_A(a_, db, 0, sw0); RD_B(b0, db, sw0);
    STG_B(cn, dn, 0); STG_B(cn, dn, 1);
    BAR;
    MM16(0, a_, b0);
    BAR;
    // ph1: (mh0, kk1); stage A0,A2(c+1); vmcnt(4) retires (A1,A3)(c)
    RD_A(a_, db, 0, sw1); RD_B(b1, db, sw1);
    STG_A(cn, dn, 0); STG_A(cn, dn, 2);
    VM4; SB0; BAR;
    MM16(0, a_, b1);
    BAR;
    // ph2: (mh1, kk0) -- b0 reused; stage B2,B3(c+1)
    RD_A(a_, db, 1, sw0);
    STG_B(cn, dn, 2); STG_B(cn, dn, 3);
    BAR;
    MM16(4, a_, b0);
    BAR;
    // ph3: (mh1, kk1); stage A1,A3(c+1); boundary vmcnt(2)
    RD_A(a_, db, 1, sw1);
    STG_A(cn, dn, 1); STG_A(cn, dn, 3);
    VM2; SB0; BAR;
    MM16(4, a_, b1);
    BAR;
  }
  asm volatile("s_waitcnt vmcnt(0)" ::: "memory");  // drain dummy stages
  SB0; BAR;                                          // LDS quiescent block-wide

#undef RD_A
#undef RD_B
#undef STG_A
#undef STG_B
#undef MM16
#undef BAR
#undef SB0
#undef VM2
#undef VM4

  if constexpr (EPI == 1) {
    // out-proj epilogue: +bias -> f32
#pragma unroll
    for (int q = 0; q < 8; ++q) {
#pragma unroll
      for (int nt = 0; nt < 4; ++nt) {
        const int gc = n0 + wn * 64 + nt * 16 + lr;
        const float bb = bias[gc];
#pragma unroll
        for (int r = 0; r < 4; ++r) {
          const int gr = m0 + wm * 128 + q * 16 + lg * 4 + r;
          ((float*)outp)[(size_t)gr * 1024 + gc] = acc[q][nt][r] + bb;
        }
      }
    }
  } else {
    // ---- fused attention epilogue ----
    const int hh = (n0 >> 6) + wn;
    const int b = m0 >> 12;
    const u16* gK = KT + (size_t)(b * 16 + hh) * (96 * 64);
    const u16* gV = VT + (size_t)(b * 16 + hh) * (64 * 96);
    u16* Qs = (u16*)(lds + w * 16384);
    u16* Ps = (u16*)(lds + w * 16384 + 8192);
    u16* QBo = (u16*)outp;

    bf16x8 fk[5][2], fv[4][3];
#pragma unroll
    for (int nt = 0; nt < 5; ++nt)
#pragma unroll
      for (int ks = 0; ks < 2; ++ks)
        fk[nt][ks] = *(const bf16x8*)&gK[(nt * 16 + lr) * 64 + ks * 32 + lg * 8];
#pragma unroll
    for (int nt = 0; nt < 4; ++nt)
#pragma unroll
      for (int ks = 0; ks < 3; ++ks)
        fv[nt][ks] = *(const bf16x8*)&gV[(nt * 16 + lr) * 96 + ks * 32 + lg * 8];

    float bb[4];
#pragma unroll
    for (int nt = 0; nt < 4; ++nt) bb[nt] = bias[n0 + wn * 64 + nt * 16 + lr];

#pragma unroll
    for (int cc = 0; cc < 4; ++cc) {
#pragma unroll
      for (int qq = 0; qq < 2; ++qq)
#pragma unroll
        for (int nt = 0; nt < 4; ++nt)
#pragma unroll
          for (int r = 0; r < 4; ++r)
            Qs[(qq * 16 + lg * 4 + r) * 72 + nt * 16 + lr] =
                f2bf(acc[cc * 2 + qq][nt][r] + bb[nt]);

      bf16x8 aq[2][2];
#pragma unroll
      for (int qq = 0; qq < 2; ++qq)
#pragma unroll
        for (int ks = 0; ks < 2; ++ks)
          aq[qq][ks] = *(const bf16x8*)&Qs[(qq * 16 + lr) * 72 + ks * 32 + lg * 8];

      f32x4 s_[2][5] = {};
#pragma unroll
      for (int nt = 0; nt < 5; ++nt)
#pragma unroll
        for (int ks = 0; ks < 2; ++ks)
#pragma unroll
          for (int qq = 0; qq < 2; ++qq)
            s_[qq][nt] = __builtin_amdgcn_mfma_f32_16x16x32_bf16(aq[qq][ks], fk[nt][ks], s_[qq][nt], 0, 0, 0);
#pragma unroll
      for (int qq = 0; qq < 2; ++qq)
#pragma unroll
        for (int nt = 0; nt < 5; ++nt)
#pragma unroll
          for (int r = 0; r < 4; ++r)
            s_[qq][nt][r] *= 0.125f;
      if (lr >= 13) {
#pragma unroll
        for (int qq = 0; qq < 2; ++qq)
#pragma unroll
          for (int r = 0; r < 4; ++r)
            s_[qq][4][r] = -1e30f;
      }

      float ri[2][4];
#pragma unroll
      for (int qq = 0; qq < 2; ++qq) {
#pragma unroll
        for (int r = 0; r < 4; ++r) {
          float m1 = s_[qq][0][r];
#pragma unroll
          for (int nt = 1; nt < 5; ++nt) m1 = fmaxf(m1, s_[qq][nt][r]);
          m1 = fmaxf(m1, __shfl_xor(m1, 1, 64));
          m1 = fmaxf(m1, __shfl_xor(m1, 2, 64));
          m1 = fmaxf(m1, __shfl_xor(m1, 4, 64));
          m1 = fmaxf(m1, __shfl_xor(m1, 8, 64));
          float s1 = 0.f;
#pragma unroll
          for (int nt = 0; nt < 5; ++nt) {
            float e = __expf(s_[qq][nt][r] - m1);
            s_[qq][nt][r] = e;
            s1 += e;
          }
          s1 += __shfl_xor(s1, 1, 64);
          s1 += __shfl_xor(s1, 2, 64);
          s1 += __shfl_xor(s1, 4, 64);
          s1 += __shfl_xor(s1, 8, 64);
          ri[qq][r] = 1.0f / s1;
        }
      }

#pragma unroll
      for (int qq = 0; qq < 2; ++qq)
#pragma unroll
        for (int nt = 0; nt < 5; ++nt)
#pragma unroll
          for (int r = 0; r < 4; ++r)
            Ps[(qq * 16 + lg * 4 + r) * 104 + nt * 16 + lr] = f2bf(s_[qq][nt][r] * ri[qq][r]);
#pragma unroll
      for (int qq = 0; qq < 2; ++qq)
#pragma unroll
        for (int r = 0; r < 4; ++r)
          Ps[(qq * 16 + lg * 4 + r) * 104 + 80 + lr] = 0;

      f32x4 o_[2][4] = {};
#pragma unroll
      for (int ks = 0; ks < 3; ++ks) {
        bf16x8 ap[2];
#pragma unroll
        for (int qq = 0; qq < 2; ++qq)
          ap[qq] = *(const bf16x8*)&Ps[(qq * 16 + lr) * 104 + ks * 32 + lg * 8];
#pragma unroll
        for (int nt = 0; nt < 4; ++nt)
#pragma unroll
          for (int qq = 0; qq < 2; ++qq)
            o_[qq][nt] = __builtin_amdgcn_mfma_f32_16x16x32_bf16(ap[qq], fv[nt][ks], o_[qq][nt], 0, 0, 0);
      }

#pragma unroll
      for (int qq = 0; qq < 2; ++qq)
#pragma unroll
        for (int nt = 0; nt < 4; ++nt)
#pragma unroll
          for (int r = 0; r < 4; ++r)
            QBo[(size_t)(m0 + wm * 128 + cc * 32 + qq * 16 + lg * 4 + r) * 1024
                + hh * 64 + nt * 16 + lr] = f2bf(o_[qq][nt][r]);
    }
  }
}

// ---------------- launch ----------------

extern "C" void kernel_launch(void* const* d_in, const int* in_sizes, int n_in,
                              void* d_out, int out_size, void* d_ws, size_t ws_size,
                              hipStream_t stream) {
  const float* x  = (const float*)d_in[0];
  const float* y  = (const float*)d_in[1];
  const float* wq = (const float*)d_in[2];
  const float* bq = (const float*)d_in[3];
  const float* wk = (const float*)d_in[4];
  const float* bk = (const float*)d_in[5];
  const float* wv = (const float*)d_in[6];
  const float* bv = (const float*)d_in[7];
  const float* wo = (const float*)d_in[8];
  const float* bo = (const float*)d_in[9];

  char* ws = (char*)d_ws;
  u16* QB   = (u16*)(ws + 0);            // 65536x1024 bf16 = 128 MB (attn-out)
  u16* WQ1T = (u16*)(ws + 134217728);    // [1024][1024] bf16, 2 MB
  u16* WO1T = (u16*)(ws + 136314880);    // 2 MB
  u16* WK1T = (u16*)(ws + 138412032);    // [1024][768] bf16, 1.5 MB
  u16* WV1T = (u16*)(ws + 139984896);    // 1.5 MB
  u16* YB   = (u16*)(ws + 141557760);    // [1232][768] bf16, 1.85 MB
  u16* KT   = (u16*)(ws + 143654912);    // [16][16][96][64] bf16, 3 MB
  u16* VT   = (u16*)(ws + 146800640);    // [16][16][64][96] bf16, 3 MB

  u16*   XB  = (u16*)d_out;   // x as bf16, first 128 MB of d_out (consumed before final write)
  float* OUT = (float*)d_out;

  // prep
  k_zero<<<768, 256, 0, stream>>>((u16x8*)KT, 393216);          // zero KT+VT (adjacent, 6 MB)
  k_cvt_x<<<4096, 256, 0, stream>>>(x, XB, 16777216);
  k_prep_wt<<<896, 256, 0, stream>>>(wq, wo, wk, wv, WQ1T, WO1T, WK1T, WV1T);
  k_prep_y<<<924, 256, 0, stream>>>(y, YB, 236544);

  // K+V projections (one launch): M=1232, K=768
  k_gemm_kv<<<160, 256, 0, stream>>>(YB, WK1T, bk, KT, WV1T, bv, VT);

  // Q projection + FUSED ATTENTION -> QB
  gemm8p<0><<<1024, 512, 0, stream>>>(XB, WQ1T, bq, QB, KT, VT);

  // output projection -> f32 d_out
  gemm8p<1><<<1024, 512, 0, stream>>>(QB, WO1T, bo, OUT, nullptr, nullptr);
}

// Round 19
// 486.436 us; speedup vs baseline: 1.0453x; 1.0064x over previous
//
#include <hip/hip_runtime.h>

typedef unsigned short u16;
typedef __attribute__((ext_vector_type(4))) float f32x4;
typedef __attribute__((ext_vector_type(8))) short bf16x8;
typedef __attribute__((ext_vector_type(8))) unsigned short u16x8;
typedef __attribute__((ext_vector_type(4))) unsigned short u16x4;

__device__ __forceinline__ u16 f2bf(float f) {
  union { float f; unsigned u; } v; v.f = f;
  unsigned r = v.u + 0x7FFFu + ((v.u >> 16) & 1u);
  return (u16)(r >> 16);
}
__device__ __forceinline__ float bf2f(u16 h) {
  union { unsigned u; float f; } v; v.u = ((unsigned)h) << 16; return v.f;
}

__device__ __forceinline__ void gload_lds16(const void* g, void* l) {
  __builtin_amdgcn_global_load_lds((const __attribute__((address_space(1))) void*)g,
                                   (__attribute__((address_space(3))) void*)l, 16, 0, 0);
}

// ---------------- prep kernels ----------------

__global__ void k_zero(u16x8* __restrict__ p, int n8) {
  int i = blockIdx.x * blockDim.x + threadIdx.x;
  int stride = gridDim.x * blockDim.x;
  u16x8 z = (u16x8)0;
  for (; i < n8; i += stride) p[i] = z;
}

__global__ void k_cvt_x(const float* __restrict__ in, u16* __restrict__ out, int n4) {
  int i = blockIdx.x * blockDim.x + threadIdx.x;
  int stride = gridDim.x * blockDim.x;
  const f32x4* in4 = (const f32x4*)in;
  u16x4* out4 = (u16x4*)out;
  for (; i < n4; i += stride) {
    f32x4 v = in4[i];
    u16x4 o;
    o[0] = f2bf(v[0]); o[1] = f2bf(v[1]); o[2] = f2bf(v[2]); o[3] = f2bf(v[3]);
    out4[i] = o;
  }
}

// LDS-tiled transpose: w [K][1024] f32 -> outT [1024][K] bf16, 64x64 tiles.
__global__ void k_prep_wt(const float* __restrict__ wq, const float* __restrict__ wo,
                          const float* __restrict__ wk, const float* __restrict__ wv,
                          u16* __restrict__ WQ1T, u16* __restrict__ WO1T,
                          u16* __restrict__ WK1T, u16* __restrict__ WV1T) {
  __shared__ u16 tile[64][72];
  int bid = blockIdx.x;
  const float* w; u16* o; int K;
  if (bid < 256)      { w = wq; o = WQ1T; K = 1024; }
  else if (bid < 512) { w = wo; o = WO1T; K = 1024; bid -= 256; }
  else if (bid < 704) { w = wk; o = WK1T; K = 768;  bid -= 512; }
  else                { w = wv; o = WV1T; K = 768;  bid -= 704; }
  const int ti = bid >> 4, tj = bid & 15;
  const int t = threadIdx.x;
  const int r = t >> 2, cq = (t & 3) * 16;

  const float* src = w + (size_t)(ti * 64 + r) * 1024 + tj * 64 + cq;
#pragma unroll
  for (int j4 = 0; j4 < 4; ++j4) {
    f32x4 v = *(const f32x4*)(src + j4 * 4);
#pragma unroll
    for (int e = 0; e < 4; ++e) tile[r][cq + j4 * 4 + e] = f2bf(v[e]);
  }
  __syncthreads();

  u16 vals[16];
#pragma unroll
  for (int j = 0; j < 16; ++j) vals[j] = tile[cq + j][r];
  u16* dst = o + (size_t)(tj * 64 + r) * K + ti * 64 + cq;
  *(u16x8*)dst = *(u16x8*)&vals[0];
  *(u16x8*)(dst + 8) = *(u16x8*)&vals[8];
}

// y [1232][768] f32 -> yb bf16 (straight cvt)
__global__ void k_prep_y(const float* __restrict__ y, u16* __restrict__ yb, int n4) {
  int i = blockIdx.x * blockDim.x + threadIdx.x;
  int stride = gridDim.x * blockDim.x;
  const f32x4* in4 = (const f32x4*)y;
  u16x4* out4 = (u16x4*)yb;
  for (; i < n4; i += stride) {
    f32x4 v = in4[i];
    u16x4 o;
    o[0] = f2bf(v[0]); o[1] = f2bf(v[1]); o[2] = f2bf(v[2]); o[3] = f2bf(v[3]);
    out4[i] = o;
  }
}

// ---------------- K+V projections, merged, m97-style 128^2 ----------------
__global__ __launch_bounds__(256, 2) void k_gemm_kv(
    const u16* __restrict__ A,
    const u16* __restrict__ BK1, const float* __restrict__ bkb, u16* __restrict__ KTo,
    const u16* __restrict__ BV1, const float* __restrict__ bvb, u16* __restrict__ VTo)
{
  const int M = 1232, Kdim = 768;
  __shared__ u16 sA[128 * 32];
  __shared__ u16 sB[128 * 32];
  const int t = threadIdx.x;
  const int half = blockIdx.x >= 80;
  const int bb = blockIdx.x - half * 80;
  const u16* B = half ? BV1 : BK1;
  const float* bias = half ? bvb : bkb;
  u16* outp = half ? VTo : KTo;
  const int bm = bb / 8, bn = bb % 8;
  const int m0 = bm * 128, n0 = bn * 128;
  const int l = t & 63, wv_ = t >> 6;
  const int lr = l & 15, lg = l >> 4;
  const int wm = (wv_ >> 1) * 64, wn = (wv_ & 1) * 64;

  const int srow = t >> 2;
  const int ssw = ((t >> 2) & 3) ^ ((t >> 4) & 3);
  const int scol = ((t & 3) ^ ssw) * 8;
  char* ldsA = (char*)sA;
  char* ldsB = (char*)sB;
  const int ldsoff = wv_ * 1024;

  const int swl = (lr & 3) ^ ((lr >> 2) & 3);
  const int rds = (lg ^ swl) * 8;

  f32x4 acc[4][4] = {};

  for (int kt = 0; kt < Kdim / 32; ++kt) {
    const int k0 = kt * 32;
    __syncthreads();
    {
      int r1 = m0 + srow;       if (r1 > M - 1) r1 = M - 1;
      int r2 = m0 + 64 + srow;  if (r2 > M - 1) r2 = M - 1;
      gload_lds16(A + (size_t)r1 * Kdim + k0 + scol, ldsA + 0    + ldsoff);
      gload_lds16(A + (size_t)r2 * Kdim + k0 + scol, ldsA + 4096 + ldsoff);
      gload_lds16(B + (size_t)(n0 + srow) * Kdim + k0 + scol,      ldsB + 0    + ldsoff);
      gload_lds16(B + (size_t)(n0 + 64 + srow) * Kdim + k0 + scol, ldsB + 4096 + ldsoff);
    }
    __syncthreads();
    bf16x8 af[4], bfr[4];
#pragma unroll
    for (int mt = 0; mt < 4; ++mt)
      af[mt] = *(const bf16x8*)&sA[(wm + mt * 16 + lr) * 32 + rds];
#pragma unroll
    for (int nt = 0; nt < 4; ++nt)
      bfr[nt] = *(const bf16x8*)&sB[(wn + nt * 16 + lr) * 32 + rds];
#pragma unroll
    for (int mt = 0; mt < 4; ++mt)
#pragma unroll
      for (int nt = 0; nt < 4; ++nt)
        acc[mt][nt] = __builtin_amdgcn_mfma_f32_16x16x32_bf16(af[mt], bfr[nt], acc[mt][nt], 0, 0, 0);
  }

#pragma unroll
  for (int mt = 0; mt < 4; ++mt) {
#pragma unroll
    for (int nt = 0; nt < 4; ++nt) {
      const int gc = n0 + wn + nt * 16 + lr;
      const float bb2 = bias[gc];
#pragma unroll
      for (int r = 0; r < 4; ++r) {
        const int gr = m0 + wm + mt * 16 + lg * 4 + r;
        const float v = acc[mt][nt][r] + bb2;
        if (gr < M) {
          int bI = gr / 77, s = gr - bI * 77;
          int hh = gc >> 6, d = gc & 63;
          if (!half)
            outp[(((size_t)bI * 16 + hh) * 96 + s) * 64 + d] = f2bf(v);
          else
            outp[(((size_t)bI * 16 + hh) * 64 + d) * 96 + s] = f2bf(v);
        }
      }
    }
  }
}

// ---------------- big GEMM: 256x256, BK=64, 2-BARRIERS-PER-TILE counted-vmcnt pipeline ----------------
// The r18 fix: vmcnt is PER-WAVE but each LDS block is written by all 8 waves' DMA slices,
// so every counted wait must be FOLLOWED BY A BARRIER to make retirement cross-wave visible.
// Per tile c (read db, stage c+1 into dn):
//   sub0: 24 ds_reads (mh0 kk0+kk1, B kk0+kk1) ; STG B0-3,A0,A2(c+1) ; 64 MFMA(mh0)
//         vmcnt(6) [retires A1,A3(c); keeps c+1's 6 sub0-stages flying] ; BAR
//   sub1: 8 ds_reads (mh1) ; STG A1,A3(c+1) ; 64 MFMA(mh1)
//         vmcnt(2) [keeps exactly A1,A3(c+1)] ; BAR
// Ledger induction: 2 -> +6=8 -> VM6 -> 6 -> +2=8 -> VM2 -> 2. Prologue stages tile0 as
// B0-3,A0,A2,A1,A3 then VM2 -> same invariant. A0,A2(c+1) get sub0+sub1 (~1200cy) HBM cover.
// EPI 0: fused attention epilogue (r15 verbatim). EPI 1: +bias -> f32.
template <int EPI>
__global__ __launch_bounds__(512, 2) void gemm8p(
    const u16* __restrict__ A, const u16* __restrict__ Bp,
    const float* __restrict__ bias, void* __restrict__ outp,
    const u16* __restrict__ KT, const u16* __restrict__ VT)
{
  __shared__ char lds[131072];
  const int t = threadIdx.x;
  const int cpx = (int)gridDim.x >> 3;
  const int swz = ((int)blockIdx.x & 7) * cpx + ((int)blockIdx.x >> 3);
  const int bm = swz >> 2, bn = swz & 3;
  const int m0 = bm * 256, n0 = bn * 256;
  const int w = t >> 6, l = t & 63, lr = l & 15, lg = l >> 4;
  const int wm = w >> 2, wn = w & 3;   // 2 M-waves x 4 N-waves, wave tile 128x64

  const int srow = t >> 3;
  const int scol = ((t & 7) ^ ((t >> 3) & 7)) << 3;   // elems
  const int sw0 = ((lg) ^ (lr & 7)) << 4;
  const int sw1 = ((4 + lg) ^ (lr & 7)) << 4;
  const int abase = wm * 128 + lr;
  const int bbase = wn * 64 + lr;

  f32x4 acc[8][4] = {};

#define RD_A(dst, db, mh, ksw) { _Pragma("unroll") for (int q = 0; q < 4; ++q) \
    dst[q] = *(const bf16x8*)(lds + (db) + ((abase + (mh) * 64 + q * 16) << 7) + (ksw)); }
#define RD_B(dst, db, ksw) { _Pragma("unroll") for (int nt = 0; nt < 4; ++nt) \
    dst[nt] = *(const bf16x8*)(lds + (db) + 32768 + ((bbase + nt * 16) << 7) + (ksw)); }
#define STG_A(kt, dn, j) gload_lds16(A + (size_t)(m0 + (j) * 64 + srow) * 1024 + (kt) * 64 + scol, \
                                     lds + (dn) + (j) * 8192 + t * 16)
#define STG_B(kt, dn, j) gload_lds16(Bp + (size_t)(n0 + (j) * 64 + srow) * 1024 + (kt) * 64 + scol, \
                                     lds + (dn) + 32768 + (j) * 8192 + t * 16)
#define MM16(ab, a_, b_) { __builtin_amdgcn_s_setprio(1); \
  _Pragma("unroll") for (int q = 0; q < 4; ++q) \
    _Pragma("unroll") for (int nt = 0; nt < 4; ++nt) \
      acc[(ab) + q][nt] = __builtin_amdgcn_mfma_f32_16x16x32_bf16(a_[q], b_[nt], acc[(ab) + q][nt], 0, 0, 0); \
  __builtin_amdgcn_s_setprio(0); }
#define BAR __builtin_amdgcn_s_barrier()
#define SB0 __builtin_amdgcn_sched_barrier(0)
#define VM2 asm volatile("s_waitcnt vmcnt(2)" ::: "memory")
#define VM6 asm volatile("s_waitcnt vmcnt(6)" ::: "memory")

  // prologue: stage tile 0; vmcnt(2) leaves (A1,A3)(t0) flying (steady-state invariant).
  STG_B(0, 0, 0); STG_B(0, 0, 1); STG_B(0, 0, 2); STG_B(0, 0, 3);
  STG_A(0, 0, 0); STG_A(0, 0, 2);
  STG_A(0, 0, 1); STG_A(0, 0, 3);
  VM2; SB0; BAR;

#pragma unroll 2
  for (int c = 0; c < 16; ++c) {
    const int db = (c & 1) * 65536, dn = db ^ 65536;
    int cn = c + 1; if (cn > 15) cn = 15;   // tail: dummy re-stage into dead buffer
    bf16x8 a0_[4], a1_[4], b0[4], b1[4];
    // sub0: mh0 (kk0+kk1); stage B0-3,A0,A2(c+1)
    RD_A(a0_, db, 0, sw0); RD_A(a1_, db, 0, sw1);
    RD_B(b0, db, sw0); RD_B(b1, db, sw1);
    STG_B(cn, dn, 0); STG_B(cn, dn, 1); STG_B(cn, dn, 2); STG_B(cn, dn, 3);
    STG_A(cn, dn, 0); STG_A(cn, dn, 2);
    MM16(0, a0_, b0);
    MM16(0, a1_, b1);
    // retire A1,A3(c) across ALL waves before mh1 reads (wait + barrier)
    VM6; SB0; BAR;
    // sub1: mh1; stage A1,A3(c+1)
    RD_A(a0_, db, 1, sw0); RD_A(a1_, db, 1, sw1);
    STG_A(cn, dn, 1); STG_A(cn, dn, 3);
    MM16(4, a0_, b0);
    MM16(4, a1_, b1);
    // boundary: keep exactly A1,A3(c+1) in flight (wait + barrier)
    VM2; SB0; BAR;
  }
  asm volatile("s_waitcnt vmcnt(0)" ::: "memory");  // drain dummy stages
  SB0; BAR;                                          // LDS quiescent block-wide

#undef RD_A
#undef RD_B
#undef STG_A
#undef STG_B
#undef MM16
#undef BAR
#undef SB0
#undef VM2
#undef VM6

  if constexpr (EPI == 1) {
    // out-proj epilogue: +bias -> f32
#pragma unroll
    for (int q = 0; q < 8; ++q) {
#pragma unroll
      for (int nt = 0; nt < 4; ++nt) {
        const int gc = n0 + wn * 64 + nt * 16 + lr;
        const float bb = bias[gc];
#pragma unroll
        for (int r = 0; r < 4; ++r) {
          const int gr = m0 + wm * 128 + q * 16 + lg * 4 + r;
          ((float*)outp)[(size_t)gr * 1024 + gc] = acc[q][nt][r] + bb;
        }
      }
    }
  } else {
    // ---- fused attention epilogue (r15 verbatim) ----
    const int hh = (n0 >> 6) + wn;
    const int b = m0 >> 12;
    const u16* gK = KT + (size_t)(b * 16 + hh) * (96 * 64);
    const u16* gV = VT + (size_t)(b * 16 + hh) * (64 * 96);
    u16* Qs = (u16*)(lds + w * 16384);
    u16* Ps = (u16*)(lds + w * 16384 + 8192);
    u16* QBo = (u16*)outp;

    bf16x8 fk[5][2], fv[4][3];
#pragma unroll
    for (int nt = 0; nt < 5; ++nt)
#pragma unroll
      for (int ks = 0; ks < 2; ++ks)
        fk[nt][ks] = *(const bf16x8*)&gK[(nt * 16 + lr) * 64 + ks * 32 + lg * 8];
#pragma unroll
    for (int nt = 0; nt < 4; ++nt)
#pragma unroll
      for (int ks = 0; ks < 3; ++ks)
        fv[nt][ks] = *(const bf16x8*)&gV[(nt * 16 + lr) * 96 + ks * 32 + lg * 8];

    float bb[4];
#pragma unroll
    for (int nt = 0; nt < 4; ++nt) bb[nt] = bias[n0 + wn * 64 + nt * 16 + lr];

#pragma unroll
    for (int cc = 0; cc < 4; ++cc) {
#pragma unroll
      for (int qq = 0; qq < 2; ++qq)
#pragma unroll
        for (int nt = 0; nt < 4; ++nt)
#pragma unroll
          for (int r = 0; r < 4; ++r)
            Qs[(qq * 16 + lg * 4 + r) * 72 + nt * 16 + lr] =
                f2bf(acc[cc * 2 + qq][nt][r] + bb[nt]);

      bf16x8 aq[2][2];
#pragma unroll
      for (int qq = 0; qq < 2; ++qq)
#pragma unroll
        for (int ks = 0; ks < 2; ++ks)
          aq[qq][ks] = *(const bf16x8*)&Qs[(qq * 16 + lr) * 72 + ks * 32 + lg * 8];

      f32x4 s_[2][5] = {};
#pragma unroll
      for (int nt = 0; nt < 5; ++nt)
#pragma unroll
        for (int ks = 0; ks < 2; ++ks)
#pragma unroll
          for (int qq = 0; qq < 2; ++qq)
            s_[qq][nt] = __builtin_amdgcn_mfma_f32_16x16x32_bf16(aq[qq][ks], fk[nt][ks], s_[qq][nt], 0, 0, 0);
#pragma unroll
      for (int qq = 0; qq < 2; ++qq)
#pragma unroll
        for (int nt = 0; nt < 5; ++nt)
#pragma unroll
          for (int r = 0; r < 4; ++r)
            s_[qq][nt][r] *= 0.125f;
      if (lr >= 13) {
#pragma unroll
        for (int qq = 0; qq < 2; ++qq)
#pragma unroll
          for (int r = 0; r < 4; ++r)
            s_[qq][4][r] = -1e30f;
      }

      float ri[2][4];
#pragma unroll
      for (int qq = 0; qq < 2; ++qq) {
#pragma unroll
        for (int r = 0; r < 4; ++r) {
          float m1 = s_[qq][0][r];
#pragma unroll
          for (int nt = 1; nt < 5; ++nt) m1 = fmaxf(m1, s_[qq][nt][r]);
          m1 = fmaxf(m1, __shfl_xor(m1, 1, 64));
          m1 = fmaxf(m1, __shfl_xor(m1, 2, 64));
          m1 = fmaxf(m1, __shfl_xor(m1, 4, 64));
          m1 = fmaxf(m1, __shfl_xor(m1, 8, 64));
          float s1 = 0.f;
#pragma unroll
          for (int nt = 0; nt < 5; ++nt) {
            float e = __expf(s_[qq][nt][r] - m1);
            s_[qq][nt][r] = e;
            s1 += e;
          }
          s1 += __shfl_xor(s1, 1, 64);
          s1 += __shfl_xor(s1, 2, 64);
          s1 += __shfl_xor(s1, 4, 64);
          s1 += __shfl_xor(s1, 8, 64);
          ri[qq][r] = 1.0f / s1;
        }
      }

#pragma unroll
      for (int qq = 0; qq < 2; ++qq)
#pragma unroll
        for (int nt = 0; nt < 5; ++nt)
#pragma unroll
          for (int r = 0; r < 4; ++r)
            Ps[(qq * 16 + lg * 4 + r) * 104 + nt * 16 + lr] = f2bf(s_[qq][nt][r] * ri[qq][r]);
#pragma unroll
      for (int qq = 0; qq < 2; ++qq)
#pragma unroll
        for (int r = 0; r < 4; ++r)
          Ps[(qq * 16 + lg * 4 + r) * 104 + 80 + lr] = 0;

      f32x4 o_[2][4] = {};
#pragma unroll
      for (int ks = 0; ks < 3; ++ks) {
        bf16x8 ap[2];
#pragma unroll
        for (int qq = 0; qq < 2; ++qq)
          ap[qq] = *(const bf16x8*)&Ps[(qq * 16 + lr) * 104 + ks * 32 + lg * 8];
#pragma unroll
        for (int nt = 0; nt < 4; ++nt)
#pragma unroll
          for (int qq = 0; qq < 2; ++qq)
            o_[qq][nt] = __builtin_amdgcn_mfma_f32_16x16x32_bf16(ap[qq], fv[nt][ks], o_[qq][nt], 0, 0, 0);
      }

#pragma unroll
      for (int qq = 0; qq < 2; ++qq)
#pragma unroll
        for (int nt = 0; nt < 4; ++nt)
#pragma unroll
          for (int r = 0; r < 4; ++r)
            QBo[(size_t)(m0 + wm * 128 + cc * 32 + qq * 16 + lg * 4 + r) * 1024
                + hh * 64 + nt * 16 + lr] = f2bf(o_[qq][nt][r]);
    }
  }
}

// ---------------- launch ----------------

extern "C" void kernel_launch(void* const* d_in, const int* in_sizes, int n_in,
                              void* d_out, int out_size, void* d_ws, size_t ws_size,
                              hipStream_t stream) {
  const float* x  = (const float*)d_in[0];
  const float* y  = (const float*)d_in[1];
  const float* wq = (const float*)d_in[2];
  const float* bq = (const float*)d_in[3];
  const float* wk = (const float*)d_in[4];
  const float* bk = (const float*)d_in[5];
  const float* wv = (const float*)d_in[6];
  const float* bv = (const float*)d_in[7];
  const float* wo = (const float*)d_in[8];
  const float* bo = (const float*)d_in[9];

  char* ws = (char*)d_ws;
  u16* QB   = (u16*)(ws + 0);            // 65536x1024 bf16 = 128 MB (attn-out)
  u16* WQ1T = (u16*)(ws + 134217728);    // [1024][1024] bf16, 2 MB
  u16* WO1T = (u16*)(ws + 136314880);    // 2 MB
  u16* WK1T = (u16*)(ws + 138412032);    // [1024][768] bf16, 1.5 MB
  u16* WV1T = (u16*)(ws + 139984896);    // 1.5 MB
  u16* YB   = (u16*)(ws + 141557760);    // [1232][768] bf16, 1.85 MB
  u16* KT   = (u16*)(ws + 143654912);    // [16][16][96][64] bf16, 3 MB
  u16* VT   = (u16*)(ws + 146800640);    // [16][16][64][96] bf16, 3 MB

  u16*   XB  = (u16*)d_out;   // x as bf16, first 128 MB of d_out (consumed before final write)
  float* OUT = (float*)d_out;

  // prep
  k_zero<<<768, 256, 0, stream>>>((u16x8*)KT, 393216);          // zero KT+VT (adjacent, 6 MB)
  k_cvt_x<<<4096, 256, 0, stream>>>(x, XB, 16777216);
  k_prep_wt<<<896, 256, 0, stream>>>(wq, wo, wk, wv, WQ1T, WO1T, WK1T, WV1T);
  k_prep_y<<<924, 256, 0, stream>>>(y, YB, 236544);

  // K+V projections (one launch): M=1232, K=768
  k_gemm_kv<<<160, 256, 0, stream>>>(YB, WK1T, bk, KT, WV1T, bv, VT);

  // Q projection + FUSED ATTENTION -> QB
  gemm8p<0><<<1024, 512, 0, stream>>>(XB, WQ1T, bq, QB, KT, VT);

  // output projection -> f32 d_out
  gemm8p<1><<<1024, 512, 0, stream>>>(QB, WO1T, bo, OUT, nullptr, nullptr);
}

// Round 21
// 482.184 us; speedup vs baseline: 1.0545x; 1.0088x over previous
//
#include <hip/hip_runtime.h>

typedef unsigned short u16;
typedef __attribute__((ext_vector_type(4))) float f32x4;
typedef __attribute__((ext_vector_type(8))) short bf16x8;
typedef __attribute__((ext_vector_type(8))) unsigned short u16x8;
typedef __attribute__((ext_vector_type(4))) unsigned short u16x4;

__device__ __forceinline__ u16 f2bf(float f) {
  union { float f; unsigned u; } v; v.f = f;
  unsigned r = v.u + 0x7FFFu + ((v.u >> 16) & 1u);
  return (u16)(r >> 16);
}
__device__ __forceinline__ float bf2f(u16 h) {
  union { unsigned u; float f; } v; v.u = ((unsigned)h) << 16; return v.f;
}

__device__ __forceinline__ void gload_lds16(const void* g, void* l) {
  __builtin_amdgcn_global_load_lds((const __attribute__((address_space(1))) void*)g,
                                   (__attribute__((address_space(3))) void*)l, 16, 0, 0);
}

// ---------------- merged prep kernel (block-range dispatch) ----------------
// [0,896)      : weight transposes (LDS-tiled, 64x64) wq/wo/wk/wv -> [N][K] bf16
// [896,4992)   : x f32 -> bf16 (grid-stride over 16777216 f32x4-groups; x = 67108864 floats)
// [4992,5916)  : y f32 -> bf16 (924 virtual blocks, 1 group/thread)
// [5916,6684)  : zero KT+VT (768 virtual blocks)
__global__ __launch_bounds__(256) void k_prep(
    const float* __restrict__ x, const float* __restrict__ y,
    const float* __restrict__ wq, const float* __restrict__ wo,
    const float* __restrict__ wk, const float* __restrict__ wv,
    u16* __restrict__ XB, u16* __restrict__ YB,
    u16* __restrict__ WQ1T, u16* __restrict__ WO1T,
    u16* __restrict__ WK1T, u16* __restrict__ WV1T,
    u16x8* __restrict__ ZP)
{
  __shared__ u16 tile[64][72];
  const int t = threadIdx.x;
  int bid = blockIdx.x;

  if (bid < 896) {
    // weight transpose
    const float* w; u16* o; int K;
    if (bid < 256)      { w = wq; o = WQ1T; K = 1024; }
    else if (bid < 512) { w = wo; o = WO1T; K = 1024; bid -= 256; }
    else if (bid < 704) { w = wk; o = WK1T; K = 768;  bid -= 512; }
    else                { w = wv; o = WV1T; K = 768;  bid -= 704; }
    const int ti = bid >> 4, tj = bid & 15;
    const int r = t >> 2, cq = (t & 3) * 16;

    const float* src = w + (size_t)(ti * 64 + r) * 1024 + tj * 64 + cq;
#pragma unroll
    for (int j4 = 0; j4 < 4; ++j4) {
      f32x4 v = *(const f32x4*)(src + j4 * 4);
#pragma unroll
      for (int e = 0; e < 4; ++e) tile[r][cq + j4 * 4 + e] = f2bf(v[e]);
    }
    __syncthreads();

    u16 vals[16];
#pragma unroll
    for (int j = 0; j < 16; ++j) vals[j] = tile[cq + j][r];
    u16* dst = o + (size_t)(tj * 64 + r) * K + ti * 64 + cq;
    *(u16x8*)dst = *(u16x8*)&vals[0];
    *(u16x8*)(dst + 8) = *(u16x8*)&vals[8];
  } else if (bid < 4992) {
    // cvt x: x = 67108864 floats = 16777216 f32x4-groups; 4096 virtual blocks grid-stride
    const int vb = bid - 896;
    const f32x4* in4 = (const f32x4*)x;
    u16x4* out4 = (u16x4*)XB;
    const int stride = 4096 * 256;
    for (int i = vb * 256 + t; i < 16777216; i += stride) {
      f32x4 v = in4[i];
      u16x4 o;
      o[0] = f2bf(v[0]); o[1] = f2bf(v[1]); o[2] = f2bf(v[2]); o[3] = f2bf(v[3]);
      out4[i] = o;
    }
  } else if (bid < 5916) {
    // cvt y: 946176 floats = 236544 x4-groups, 924 virtual blocks, exactly 1/thread
    const int vb = bid - 4992;
    const int i = vb * 256 + t;
    f32x4 v = ((const f32x4*)y)[i];
    u16x4 o;
    o[0] = f2bf(v[0]); o[1] = f2bf(v[1]); o[2] = f2bf(v[2]); o[3] = f2bf(v[3]);
    ((u16x4*)YB)[i] = o;
  } else {
    // zero KT+VT: 393216 u16x8 elems, 768 virtual blocks
    const int vb = bid - 5916;
    const int stride = 768 * 256;
    u16x8 z = (u16x8)0;
    for (int i = vb * 256 + t; i < 393216; i += stride) ZP[i] = z;
  }
}

// ---------------- K+V projections, merged, m97-style 128^2 ----------------
__global__ __launch_bounds__(256, 2) void k_gemm_kv(
    const u16* __restrict__ A,
    const u16* __restrict__ BK1, const float* __restrict__ bkb, u16* __restrict__ KTo,
    const u16* __restrict__ BV1, const float* __restrict__ bvb, u16* __restrict__ VTo)
{
  const int M = 1232, Kdim = 768;
  __shared__ u16 sA[128 * 32];
  __shared__ u16 sB[128 * 32];
  const int t = threadIdx.x;
  const int half = blockIdx.x >= 80;
  const int bb = blockIdx.x - half * 80;
  const u16* B = half ? BV1 : BK1;
  const float* bias = half ? bvb : bkb;
  u16* outp = half ? VTo : KTo;
  const int bm = bb / 8, bn = bb % 8;
  const int m0 = bm * 128, n0 = bn * 128;
  const int l = t & 63, wv_ = t >> 6;
  const int lr = l & 15, lg = l >> 4;
  const int wm = (wv_ >> 1) * 64, wn = (wv_ & 1) * 64;

  const int srow = t >> 2;
  const int ssw = ((t >> 2) & 3) ^ ((t >> 4) & 3);
  const int scol = ((t & 3) ^ ssw) * 8;
  char* ldsA = (char*)sA;
  char* ldsB = (char*)sB;
  const int ldsoff = wv_ * 1024;

  const int swl = (lr & 3) ^ ((lr >> 2) & 3);
  const int rds = (lg ^ swl) * 8;

  f32x4 acc[4][4] = {};

  for (int kt = 0; kt < Kdim / 32; ++kt) {
    const int k0 = kt * 32;
    __syncthreads();
    {
      int r1 = m0 + srow;       if (r1 > M - 1) r1 = M - 1;
      int r2 = m0 + 64 + srow;  if (r2 > M - 1) r2 = M - 1;
      gload_lds16(A + (size_t)r1 * Kdim + k0 + scol, ldsA + 0    + ldsoff);
      gload_lds16(A + (size_t)r2 * Kdim + k0 + scol, ldsA + 4096 + ldsoff);
      gload_lds16(B + (size_t)(n0 + srow) * Kdim + k0 + scol,      ldsB + 0    + ldsoff);
      gload_lds16(B + (size_t)(n0 + 64 + srow) * Kdim + k0 + scol, ldsB + 4096 + ldsoff);
    }
    __syncthreads();
    bf16x8 af[4], bfr[4];
#pragma unroll
    for (int mt = 0; mt < 4; ++mt)
      af[mt] = *(const bf16x8*)&sA[(wm + mt * 16 + lr) * 32 + rds];
#pragma unroll
    for (int nt = 0; nt < 4; ++nt)
      bfr[nt] = *(const bf16x8*)&sB[(wn + nt * 16 + lr) * 32 + rds];
#pragma unroll
    for (int mt = 0; mt < 4; ++mt)
#pragma unroll
      for (int nt = 0; nt < 4; ++nt)
        acc[mt][nt] = __builtin_amdgcn_mfma_f32_16x16x32_bf16(af[mt], bfr[nt], acc[mt][nt], 0, 0, 0);
  }

#pragma unroll
  for (int mt = 0; mt < 4; ++mt) {
#pragma unroll
    for (int nt = 0; nt < 4; ++nt) {
      const int gc = n0 + wn + nt * 16 + lr;
      const float bb2 = bias[gc];
#pragma unroll
      for (int r = 0; r < 4; ++r) {
        const int gr = m0 + wm + mt * 16 + lg * 4 + r;
        const float v = acc[mt][nt][r] + bb2;
        if (gr < M) {
          int bI = gr / 77, s = gr - bI * 77;
          int hh = gc >> 6, d = gc & 63;
          if (!half)
            outp[(((size_t)bI * 16 + hh) * 96 + s) * 64 + d] = f2bf(v);
          else
            outp[(((size_t)bI * 16 + hh) * 64 + d) * 96 + s] = f2bf(v);
        }
      }
    }
  }
}

// ---------------- big GEMM: 256x256, BK=64, 2-barriers-per-tile counted-vmcnt (r19, frozen) ----------------
template <int EPI>
__global__ __launch_bounds__(512, 2) void gemm8p(
    const u16* __restrict__ A, const u16* __restrict__ Bp,
    const float* __restrict__ bias, void* __restrict__ outp,
    const u16* __restrict__ KT, const u16* __restrict__ VT)
{
  __shared__ char lds[131072];
  const int t = threadIdx.x;
  const int cpx = (int)gridDim.x >> 3;
  const int swz = ((int)blockIdx.x & 7) * cpx + ((int)blockIdx.x >> 3);
  const int bm = swz >> 2, bn = swz & 3;
  const int m0 = bm * 256, n0 = bn * 256;
  const int w = t >> 6, l = t & 63, lr = l & 15, lg = l >> 4;
  const int wm = w >> 2, wn = w & 3;   // 2 M-waves x 4 N-waves, wave tile 128x64

  const int srow = t >> 3;
  const int scol = ((t & 7) ^ ((t >> 3) & 7)) << 3;   // elems
  const int sw0 = ((lg) ^ (lr & 7)) << 4;
  const int sw1 = ((4 + lg) ^ (lr & 7)) << 4;
  const int abase = wm * 128 + lr;
  const int bbase = wn * 64 + lr;

  f32x4 acc[8][4] = {};

#define RD_A(dst, db, mh, ksw) { _Pragma("unroll") for (int q = 0; q < 4; ++q) \
    dst[q] = *(const bf16x8*)(lds + (db) + ((abase + (mh) * 64 + q * 16) << 7) + (ksw)); }
#define RD_B(dst, db, ksw) { _Pragma("unroll") for (int nt = 0; nt < 4; ++nt) \
    dst[nt] = *(const bf16x8*)(lds + (db) + 32768 + ((bbase + nt * 16) << 7) + (ksw)); }
#define STG_A(kt, dn, j) gload_lds16(A + (size_t)(m0 + (j) * 64 + srow) * 1024 + (kt) * 64 + scol, \
                                     lds + (dn) + (j) * 8192 + t * 16)
#define STG_B(kt, dn, j) gload_lds16(Bp + (size_t)(n0 + (j) * 64 + srow) * 1024 + (kt) * 64 + scol, \
                                     lds + (dn) + 32768 + (j) * 8192 + t * 16)
#define MM16(ab, a_, b_) { __builtin_amdgcn_s_setprio(1); \
  _Pragma("unroll") for (int q = 0; q < 4; ++q) \
    _Pragma("unroll") for (int nt = 0; nt < 4; ++nt) \
      acc[(ab) + q][nt] = __builtin_amdgcn_mfma_f32_16x16x32_bf16(a_[q], b_[nt], acc[(ab) + q][nt], 0, 0, 0); \
  __builtin_amdgcn_s_setprio(0); }
#define BAR __builtin_amdgcn_s_barrier()
#define SB0 __builtin_amdgcn_sched_barrier(0)
#define VM2 asm volatile("s_waitcnt vmcnt(2)" ::: "memory")
#define VM6 asm volatile("s_waitcnt vmcnt(6)" ::: "memory")

  // prologue: stage tile 0; vmcnt(2) leaves (A1,A3)(t0) flying (steady-state invariant).
  STG_B(0, 0, 0); STG_B(0, 0, 1); STG_B(0, 0, 2); STG_B(0, 0, 3);
  STG_A(0, 0, 0); STG_A(0, 0, 2);
  STG_A(0, 0, 1); STG_A(0, 0, 3);
  VM2; SB0; BAR;

#pragma unroll 2
  for (int c = 0; c < 16; ++c) {
    const int db = (c & 1) * 65536, dn = db ^ 65536;
    int cn = c + 1; if (cn > 15) cn = 15;   // tail: dummy re-stage into dead buffer
    bf16x8 a0_[4], a1_[4], b0[4], b1[4];
    // sub0: mh0 (kk0+kk1); stage B0-3,A0,A2(c+1)
    RD_A(a0_, db, 0, sw0); RD_A(a1_, db, 0, sw1);
    RD_B(b0, db, sw0); RD_B(b1, db, sw1);
    STG_B(cn, dn, 0); STG_B(cn, dn, 1); STG_B(cn, dn, 2); STG_B(cn, dn, 3);
    STG_A(cn, dn, 0); STG_A(cn, dn, 2);
    MM16(0, a0_, b0);
    MM16(0, a1_, b1);
    // retire A1,A3(c) across ALL waves before mh1 reads (wait + barrier)
    VM6; SB0; BAR;
    // sub1: mh1; stage A1,A3(c+1)
    RD_A(a0_, db, 1, sw0); RD_A(a1_, db, 1, sw1);
    STG_A(cn, dn, 1); STG_A(cn, dn, 3);
    MM16(4, a0_, b0);
    MM16(4, a1_, b1);
    // boundary: keep exactly A1,A3(c+1) in flight (wait + barrier)
    VM2; SB0; BAR;
  }
  asm volatile("s_waitcnt vmcnt(0)" ::: "memory");  // drain dummy stages
  SB0; BAR;                                          // LDS quiescent block-wide

#undef RD_A
#undef RD_B
#undef STG_A
#undef STG_B
#undef MM16
#undef BAR
#undef SB0
#undef VM2
#undef VM6

  if constexpr (EPI == 1) {
    // out-proj epilogue: +bias -> f32
#pragma unroll
    for (int q = 0; q < 8; ++q) {
#pragma unroll
      for (int nt = 0; nt < 4; ++nt) {
        const int gc = n0 + wn * 64 + nt * 16 + lr;
        const float bb = bias[gc];
#pragma unroll
        for (int r = 0; r < 4; ++r) {
          const int gr = m0 + wm * 128 + q * 16 + lg * 4 + r;
          ((float*)outp)[(size_t)gr * 1024 + gc] = acc[q][nt][r] + bb;
        }
      }
    }
  } else {
    // ---- fused attention epilogue (frozen) ----
    const int hh = (n0 >> 6) + wn;
    const int b = m0 >> 12;
    const u16* gK = KT + (size_t)(b * 16 + hh) * (96 * 64);
    const u16* gV = VT + (size_t)(b * 16 + hh) * (64 * 96);
    u16* Qs = (u16*)(lds + w * 16384);
    u16* Ps = (u16*)(lds + w * 16384 + 8192);
    u16* QBo = (u16*)outp;

    bf16x8 fk[5][2], fv[4][3];
#pragma unroll
    for (int nt = 0; nt < 5; ++nt)
#pragma unroll
      for (int ks = 0; ks < 2; ++ks)
        fk[nt][ks] = *(const bf16x8*)&gK[(nt * 16 + lr) * 64 + ks * 32 + lg * 8];
#pragma unroll
    for (int nt = 0; nt < 4; ++nt)
#pragma unroll
      for (int ks = 0; ks < 3; ++ks)
        fv[nt][ks] = *(const bf16x8*)&gV[(nt * 16 + lr) * 96 + ks * 32 + lg * 8];

    float bb[4];
#pragma unroll
    for (int nt = 0; nt < 4; ++nt) bb[nt] = bias[n0 + wn * 64 + nt * 16 + lr];

#pragma unroll
    for (int cc = 0; cc < 4; ++cc) {
#pragma unroll
      for (int qq = 0; qq < 2; ++qq)
#pragma unroll
        for (int nt = 0; nt < 4; ++nt)
#pragma unroll
          for (int r = 0; r < 4; ++r)
            Qs[(qq * 16 + lg * 4 + r) * 72 + nt * 16 + lr] =
                f2bf(acc[cc * 2 + qq][nt][r] + bb[nt]);

      bf16x8 aq[2][2];
#pragma unroll
      for (int qq = 0; qq < 2; ++qq)
#pragma unroll
        for (int ks = 0; ks < 2; ++ks)
          aq[qq][ks] = *(const bf16x8*)&Qs[(qq * 16 + lr) * 72 + ks * 32 + lg * 8];

      f32x4 s_[2][5] = {};
#pragma unroll
      for (int nt = 0; nt < 5; ++nt)
#pragma unroll
        for (int ks = 0; ks < 2; ++ks)
#pragma unroll
          for (int qq = 0; qq < 2; ++qq)
            s_[qq][nt] = __builtin_amdgcn_mfma_f32_16x16x32_bf16(aq[qq][ks], fk[nt][ks], s_[qq][nt], 0, 0, 0);
#pragma unroll
      for (int qq = 0; qq < 2; ++qq)
#pragma unroll
        for (int nt = 0; nt < 5; ++nt)
#pragma unroll
          for (int r = 0; r < 4; ++r)
            s_[qq][nt][r] *= 0.125f;
      if (lr >= 13) {
#pragma unroll
        for (int qq = 0; qq < 2; ++qq)
#pragma unroll
          for (int r = 0; r < 4; ++r)
            s_[qq][4][r] = -1e30f;
      }

      float ri[2][4];
#pragma unroll
      for (int qq = 0; qq < 2; ++qq) {
#pragma unroll
        for (int r = 0; r < 4; ++r) {
          float m1 = s_[qq][0][r];
#pragma unroll
          for (int nt = 1; nt < 5; ++nt) m1 = fmaxf(m1, s_[qq][nt][r]);
          m1 = fmaxf(m1, __shfl_xor(m1, 1, 64));
          m1 = fmaxf(m1, __shfl_xor(m1, 2, 64));
          m1 = fmaxf(m1, __shfl_xor(m1, 4, 64));
          m1 = fmaxf(m1, __shfl_xor(m1, 8, 64));
          float s1 = 0.f;
#pragma unroll
          for (int nt = 0; nt < 5; ++nt) {
            float e = __expf(s_[qq][nt][r] - m1);
            s_[qq][nt][r] = e;
            s1 += e;
          }
          s1 += __shfl_xor(s1, 1, 64);
          s1 += __shfl_xor(s1, 2, 64);
          s1 += __shfl_xor(s1, 4, 64);
          s1 += __shfl_xor(s1, 8, 64);
          ri[qq][r] = 1.0f / s1;
        }
      }

#pragma unroll
      for (int qq = 0; qq < 2; ++qq)
#pragma unroll
        for (int nt = 0; nt < 5; ++nt)
#pragma unroll
          for (int r = 0; r < 4; ++r)
            Ps[(qq * 16 + lg * 4 + r) * 104 + nt * 16 + lr] = f2bf(s_[qq][nt][r] * ri[qq][r]);
#pragma unroll
      for (int qq = 0; qq < 2; ++qq)
#pragma unroll
        for (int r = 0; r < 4; ++r)
          Ps[(qq * 16 + lg * 4 + r) * 104 + 80 + lr] = 0;

      f32x4 o_[2][4] = {};
#pragma unroll
      for (int ks = 0; ks < 3; ++ks) {
        bf16x8 ap[2];
#pragma unroll
        for (int qq = 0; qq < 2; ++qq)
          ap[qq] = *(const bf16x8*)&Ps[(qq * 16 + lr) * 104 + ks * 32 + lg * 8];
#pragma unroll
        for (int nt = 0; nt < 4; ++nt)
#pragma unroll
          for (int qq = 0; qq < 2; ++qq)
            o_[qq][nt] = __builtin_amdgcn_mfma_f32_16x16x32_bf16(ap[qq], fv[nt][ks], o_[qq][nt], 0, 0, 0);
      }

#pragma unroll
      for (int qq = 0; qq < 2; ++qq)
#pragma unroll
        for (int nt = 0; nt < 4; ++nt)
#pragma unroll
          for (int r = 0; r < 4; ++r)
            QBo[(size_t)(m0 + wm * 128 + cc * 32 + qq * 16 + lg * 4 + r) * 1024
                + hh * 64 + nt * 16 + lr] = f2bf(o_[qq][nt][r]);
    }
  }
}

// ---------------- launch ----------------

extern "C" void kernel_launch(void* const* d_in, const int* in_sizes, int n_in,
                              void* d_out, int out_size, void* d_ws, size_t ws_size,
                              hipStream_t stream) {
  const float* x  = (const float*)d_in[0];
  const float* y  = (const float*)d_in[1];
  const float* wq = (const float*)d_in[2];
  const float* bq = (const float*)d_in[3];
  const float* wk = (const float*)d_in[4];
  const float* bk = (const float*)d_in[5];
  const float* wv = (const float*)d_in[6];
  const float* bv = (const float*)d_in[7];
  const float* wo = (const float*)d_in[8];
  const float* bo = (const float*)d_in[9];

  char* ws = (char*)d_ws;
  u16* QB   = (u16*)(ws + 0);            // 65536x1024 bf16 = 128 MB (attn-out)
  u16* WQ1T = (u16*)(ws + 134217728);    // [1024][1024] bf16, 2 MB
  u16* WO1T = (u16*)(ws + 136314880);    // 2 MB
  u16* WK1T = (u16*)(ws + 138412032);    // [1024][768] bf16, 1.5 MB
  u16* WV1T = (u16*)(ws + 139984896);    // 1.5 MB
  u16* YB   = (u16*)(ws + 141557760);    // [1232][768] bf16, 1.85 MB
  u16* KT   = (u16*)(ws + 143654912);    // [16][16][96][64] bf16, 3 MB
  u16* VT   = (u16*)(ws + 146800640);    // [16][16][64][96] bf16, 3 MB

  u16*   XB  = (u16*)d_out;   // x as bf16, first 128 MB of d_out (consumed before final write)
  float* OUT = (float*)d_out;

  // merged prep: weight transposes + x/y cvt + KT/VT zero, one launch
  k_prep<<<6684, 256, 0, stream>>>(x, y, wq, wo, wk, wv,
                                   XB, YB, WQ1T, WO1T, WK1T, WV1T, (u16x8*)KT);

  // K+V projections (one launch): M=1232, K=768
  k_gemm_kv<<<160, 256, 0, stream>>>(YB, WK1T, bk, KT, WV1T, bv, VT);

  // Q projection + FUSED ATTENTION -> QB
  gemm8p<0><<<1024, 512, 0, stream>>>(XB, WQ1T, bq, QB, KT, VT);

  // output projection -> f32 d_out
  gemm8p<1><<<1024, 512, 0, stream>>>(QB, WO1T, bo, OUT, nullptr, nullptr);
}